// Round 1
// baseline (8921.213 us; speedup 1.0000x reference)
//
#include <hip/hip_runtime.h>
#include <math.h>

// Problem constants
#define TDEC 64
#define TENC 256
#define BB   32
#define HH   512
#define VV   32000

typedef short bf16x8 __attribute__((ext_vector_type(8)));
typedef float f32x4  __attribute__((ext_vector_type(4)));

__device__ __forceinline__ float bf2f(short u) {
  union { unsigned int i; float f; } c;
  c.i = ((unsigned int)(unsigned short)u) << 16;
  return c.f;
}
__device__ __forceinline__ short f2bf(float f) {
  union { float f; unsigned int i; } c; c.f = f;
  unsigned int x = c.i;
  unsigned int r = (x + 0x7fffu + ((x >> 16) & 1u)) >> 16;  // RNE
  return (short)r;
}

// ---------------------------------------------------------------------------
// Generic bf16 MFMA GEMM: C(MxN) = A(MxK) @ B(KxN), B given transposed BT[N][K]
// AMODE: 0 = A bf16 [M,K]; 1 = A f32 [M,K] (convert on stage);
//        2 = A f32 gathered rows: row r -> gsrc[gidx[(r&31)*64 + (r>>5)]*512]
// SMODE: 0 = C f32 [M,N] row-major
//        1 = KV store: bf16 at [((b*8+h)*256+s)*64+d], b=row>>8,s=row&255,h=col>>6,d=col&63
//        2 = dense store: f32 out[((row&31)*64 + (row>>5))*N + col] + bias[col]
// Tile 128x128, BK=64, 4 waves (2x2 of 64x64), 16x16x32 bf16 MFMA.
// All shapes used are exact multiples of the tile sizes (no bounds checks).
// ---------------------------------------------------------------------------
template <int AMODE, int SMODE>
__global__ __launch_bounds__(256) void gemm_k(
    const void* __restrict__ Ap, const short* __restrict__ BT,
    void* __restrict__ Cp, int M, int N, int K,
    const int* __restrict__ gidx, const float* __restrict__ gsrc,
    const float* __restrict__ bias)
{
  __shared__ short As[128 * 72];  // +8 bf16 pad per row -> conflict-reduced
  __shared__ short Bs[128 * 72];
  const int tid = threadIdx.x;
  const int n0 = blockIdx.x * 128, m0 = blockIdx.y * 128;
  const int w = tid >> 6, lane = tid & 63;
  const int wm = (w >> 1) * 64, wn = (w & 1) * 64;

  f32x4 acc[4][4] = {};

  for (int k0 = 0; k0 < K; k0 += 64) {
    // ---- stage A-tile [128][64] and B-tile [128][64] (8 bf16 per thread x4)
    #pragma unroll
    for (int i = 0; i < 4; ++i) {
      int cc = i * 256 + tid;          // 1024 chunks of 8
      int row = cc >> 3, col = (cc & 7) * 8;
      if constexpr (AMODE == 0) {
        const short* A = (const short*)Ap;
        *(bf16x8*)&As[row * 72 + col] =
            *(const bf16x8*)&A[(size_t)(m0 + row) * K + k0 + col];
      } else {
        const float* src;
        if constexpr (AMODE == 1) {
          src = (const float*)Ap + (size_t)(m0 + row) * K + k0 + col;
        } else {
          int r = m0 + row, tt = r >> 5, bb = r & 31;
          src = gsrc + (size_t)gidx[bb * 64 + tt] * 512 + k0 + col;
        }
        float4 f0 = *(const float4*)&src[0];
        float4 f1 = *(const float4*)&src[4];
        short tmp[8] = { f2bf(f0.x), f2bf(f0.y), f2bf(f0.z), f2bf(f0.w),
                         f2bf(f1.x), f2bf(f1.y), f2bf(f1.z), f2bf(f1.w) };
        *(bf16x8*)&As[row * 72 + col] = *(bf16x8*)tmp;
      }
      *(bf16x8*)&Bs[row * 72 + col] =
          *(const bf16x8*)&BT[(size_t)(n0 + row) * K + k0 + col];
    }
    __syncthreads();

    #pragma unroll
    for (int kk = 0; kk < 2; ++kk) {
      const int kcol = kk * 32 + (lane >> 4) * 8;
      bf16x8 af[4], bfr[4];
      #pragma unroll
      for (int mi = 0; mi < 4; ++mi)
        af[mi] = *(const bf16x8*)&As[(wm + mi * 16 + (lane & 15)) * 72 + kcol];
      #pragma unroll
      for (int ni = 0; ni < 4; ++ni)
        bfr[ni] = *(const bf16x8*)&Bs[(wn + ni * 16 + (lane & 15)) * 72 + kcol];
      #pragma unroll
      for (int mi = 0; mi < 4; ++mi)
        #pragma unroll
        for (int ni = 0; ni < 4; ++ni)
          acc[mi][ni] = __builtin_amdgcn_mfma_f32_16x16x32_bf16(
              af[mi], bfr[ni], acc[mi][ni], 0, 0, 0);
    }
    __syncthreads();
  }

  // ---- epilogue: C/D layout col=lane&15, row=(lane>>4)*4+reg
  #pragma unroll
  for (int mi = 0; mi < 4; ++mi) {
    #pragma unroll
    for (int ni = 0; ni < 4; ++ni) {
      int col = n0 + wn + ni * 16 + (lane & 15);
      #pragma unroll
      for (int r = 0; r < 4; ++r) {
        int row = m0 + wm + mi * 16 + ((lane >> 4) * 4) + r;
        float v = acc[mi][ni][r];
        if constexpr (SMODE == 0) {
          ((float*)Cp)[(size_t)row * N + col] = v;
        } else if constexpr (SMODE == 1) {
          int b = row >> 8, s = row & 255, h = col >> 6, d = col & 63;
          ((short*)Cp)[(size_t)((b * 8 + h) * 256 + s) * 64 + d] = f2bf(v);
        } else {
          int tt = row >> 5, b = row & 31;
          ((float*)Cp)[(size_t)(b * 64 + tt) * N + col] = v + bias[col];
        }
      }
    }
  }
}

// ---------------------------------------------------------------------------
// Tiled transpose + optional f32->bf16 convert: out[c*Rin + r] = in[r*Cin + c]
// ---------------------------------------------------------------------------
template <typename OT>
__global__ __launch_bounds__(256) void transpose_k(
    const float* __restrict__ in, OT* __restrict__ out, int Rin, int Cin)
{
  __shared__ float tile[32][33];
  int c0 = blockIdx.x * 32, r0 = blockIdx.y * 32;
  int ci = threadIdx.x & 31, rg = threadIdx.x >> 5;
  #pragma unroll
  for (int i = 0; i < 4; ++i) {
    int r = rg * 4 + i;
    tile[r][ci] = in[(size_t)(r0 + r) * Cin + c0 + ci];
  }
  __syncthreads();
  #pragma unroll
  for (int i = 0; i < 4; ++i) {
    int rr = rg * 4 + i;
    float v = tile[ci][rr];
    if constexpr (sizeof(OT) == 2)
      out[(size_t)(c0 + rr) * Rin + r0 + ci] = f2bf(v);
    else
      out[(size_t)(c0 + rr) * Rin + r0 + ci] = v;
  }
}

// ---------------------------------------------------------------------------
// init / finalize
// ---------------------------------------------------------------------------
__global__ void init_k(const float* __restrict__ hs,
                       float* __restrict__ h0, float* __restrict__ h1)
{
  int i = blockIdx.x * 256 + threadIdx.x;   // 64 blocks * 256 = 16384
  h0[i] = hs[i];
  h1[i] = hs[16384 + i];
}

__global__ void fin_k(const float* __restrict__ h0, const float* __restrict__ h1,
                      float* __restrict__ out2)
{
  int i = blockIdx.x * 256 + threadIdx.x;
  out2[i] = h0[i];
  out2[16384 + i] = h1[i];
}

// ---------------------------------------------------------------------------
// Per-step kernel 1: q = h1@Wq ; masked softmax attention ; xr = ctx@Wcmb + Eproj
// One block per batch row b, 512 threads.
// ---------------------------------------------------------------------------
__global__ __launch_bounds__(512) void attnxr_k(
    const float* __restrict__ h1, const float* __restrict__ Wq,
    const short* __restrict__ Kbf, const short* __restrict__ Vbf,
    const int* __restrict__ vlen, const float* __restrict__ Wcmb,
    const float* __restrict__ Eproj_t, float* __restrict__ xr)
{
  __shared__ float hq[512];
  __shared__ float ql[512];
  __shared__ float attn[8 * 256];
  __shared__ float rc[512];
  const int b = blockIdx.x;
  const int tid = threadIdx.x;

  hq[tid] = h1[b * 512 + tid];
  __syncthreads();

  {  // q[j] = sum_e h1[e] * Wq[e, j]   (coalesced column walk)
    float a = 0.f;
    #pragma unroll 8
    for (int e = 0; e < 512; ++e) a += hq[e] * Wq[e * 512 + tid];
    ql[tid] = a;
  }
  __syncthreads();

  const int h = tid >> 6, lane = tid & 63;
  const int L = vlen[b];
  {  // scores + masked softmax, one wave per head
    const short* Kb = Kbf + (size_t)((b * 8 + h) * 256) * 64;
    const float* qh = &ql[h * 64];
    float sc[4];
    #pragma unroll
    for (int i = 0; i < 4; ++i) {
      int s = lane + i * 64;
      const short* kr = Kb + s * 64;
      float a = 0.f;
      #pragma unroll
      for (int d0 = 0; d0 < 64; d0 += 8) {
        bf16x8 kv = *(const bf16x8*)&kr[d0];
        #pragma unroll
        for (int e = 0; e < 8; ++e) a += qh[d0 + e] * bf2f(kv[e]);
      }
      sc[i] = (s < L) ? a * 0.125f : -1e30f;
    }
    float m = fmaxf(fmaxf(sc[0], sc[1]), fmaxf(sc[2], sc[3]));
    #pragma unroll
    for (int off = 32; off > 0; off >>= 1) m = fmaxf(m, __shfl_xor(m, off, 64));
    float ex[4], sum = 0.f;
    #pragma unroll
    for (int i = 0; i < 4; ++i) {
      ex[i] = (sc[i] > -1e29f) ? __expf(sc[i] - m) : 0.f;
      sum += ex[i];
    }
    #pragma unroll
    for (int off = 32; off > 0; off >>= 1) sum += __shfl_xor(sum, off, 64);
    float inv = 1.f / sum;
    #pragma unroll
    for (int i = 0; i < 4; ++i) attn[h * 256 + lane + i * 64] = ex[i] * inv;
  }
  __syncthreads();

  {  // ctx[h,d] = sum_s attn[h,s] * V[b,h,s,d]  (coalesced in d)
    const short* Vb = Vbf + (size_t)((b * 8 + h) * 256) * 64;
    const float* at = &attn[h * 256];
    float a = 0.f;
    #pragma unroll 4
    for (int s = 0; s < 256; ++s) a += at[s] * bf2f(Vb[s * 64 + lane]);
    rc[tid] = a;
  }
  __syncthreads();

  {  // xr[j] = ctx . Wcmb[:,j] + Eproj[t,b,j]
    float a = 0.f;
    #pragma unroll 8
    for (int e = 0; e < 512; ++e) a += rc[e] * Wcmb[e * 512 + tid];
    xr[b * 512 + tid] = a + Eproj_t[b * 512 + tid];
  }
}

// ---------------------------------------------------------------------------
// Per-step kernel 2/3: LayerNorm + GRU cell + alpha residual (one layer).
// 128 blocks x 512 threads; each block owns 4 output columns j (all 32 rows),
// stages full xr and h in LDS (LN computed redundantly per block — cheap),
// 4-way K-split per dot with LDS reduction.
// ---------------------------------------------------------------------------
__global__ __launch_bounds__(512) void gru_k(
    const float* __restrict__ xr_in, float* __restrict__ xr_out,
    const float* __restrict__ h_in, float* __restrict__ h_out,
    const float* __restrict__ Wih, const float* __restrict__ Whh,
    const float* __restrict__ bih, const float* __restrict__ bhh,
    const float* __restrict__ gamma, const float* __restrict__ beta,
    const float* __restrict__ alphas, int layer, short* __restrict__ ys_t)
{
  __shared__ float xl[32 * 513];
  __shared__ float hl[32 * 513];
  __shared__ float ps[32 * 16];
  __shared__ float pq[32 * 16];
  __shared__ float mu[32];
  __shared__ float rsd[32];
  __shared__ float red[6 * 512];
  const int tid = threadIdx.x;

  {  // stage xr (with LN stats) and h
    int b = tid >> 4, seg = tid & 15;
    const float* xs = xr_in + b * 512 + seg * 32;
    const float* hs = h_in + b * 512 + seg * 32;
    float* xd = xl + b * 513 + seg * 32;
    float* hd = hl + b * 513 + seg * 32;
    float s = 0.f, q = 0.f;
    #pragma unroll
    for (int i = 0; i < 32; i += 4) {
      float4 v = *(const float4*)(xs + i);
      xd[i] = v.x; xd[i + 1] = v.y; xd[i + 2] = v.z; xd[i + 3] = v.w;
      s += v.x + v.y + v.z + v.w;
      q += v.x * v.x + v.y * v.y + v.z * v.z + v.w * v.w;
      float4 u = *(const float4*)(hs + i);
      hd[i] = u.x; hd[i + 1] = u.y; hd[i + 2] = u.z; hd[i + 3] = u.w;
    }
    ps[tid] = s; pq[tid] = q;
  }
  __syncthreads();
  if (tid < 32) {
    float s = 0.f, q = 0.f;
    #pragma unroll
    for (int i = 0; i < 16; ++i) { s += ps[tid * 16 + i]; q += pq[tid * 16 + i]; }
    float m = s * (1.f / 512.f);
    mu[tid] = m;
    rsd[tid] = rsqrtf(q * (1.f / 512.f) - m * m + 1e-5f);
  }
  __syncthreads();
  {  // normalize in place (gamma/beta applied)
    int b = tid >> 4, seg = tid & 15;
    float m = mu[b], r = rsd[b];
    float* xd = xl + b * 513 + seg * 32;
    const float* g = gamma + seg * 32;
    const float* be = beta + seg * 32;
    #pragma unroll
    for (int i = 0; i < 32; ++i) xd[i] = (xd[i] - m) * r * g[i] + be[i];
  }
  __syncthreads();

  const int b = tid & 31, qe = (tid >> 5) & 3, jj = tid >> 7;
  const int j = blockIdx.x * 4 + jj;
  const float* xb = xl + b * 513;
  const float* hb = hl + b * 513;
  const float* wiR = Wih + (size_t)j * 512;
  const float* wiZ = Wih + (size_t)(512 + j) * 512;
  const float* wiG = Wih + (size_t)(1024 + j) * 512;
  const float* whR = Whh + (size_t)j * 512;
  const float* whZ = Whh + (size_t)(512 + j) * 512;
  const float* whG = Whh + (size_t)(1024 + j) * 512;
  float aR = 0.f, aZ = 0.f, aG = 0.f, cR = 0.f, cZ = 0.f, cG = 0.f;
  const int e0 = qe * 128;
  for (int e = e0; e < e0 + 128; e += 4) {
    float4 w1 = *(const float4*)(wiR + e);
    float4 w2 = *(const float4*)(wiZ + e);
    float4 w3 = *(const float4*)(wiG + e);
    float4 u1 = *(const float4*)(whR + e);
    float4 u2 = *(const float4*)(whZ + e);
    float4 u3 = *(const float4*)(whG + e);
    float x0 = xb[e], x1 = xb[e + 1], x2 = xb[e + 2], x3 = xb[e + 3];
    float y0 = hb[e], y1 = hb[e + 1], y2 = hb[e + 2], y3 = hb[e + 3];
    aR += x0 * w1.x + x1 * w1.y + x2 * w1.z + x3 * w1.w;
    aZ += x0 * w2.x + x1 * w2.y + x2 * w2.z + x3 * w2.w;
    aG += x0 * w3.x + x1 * w3.y + x2 * w3.z + x3 * w3.w;
    cR += y0 * u1.x + y1 * u1.y + y2 * u1.z + y3 * u1.w;
    cZ += y0 * u2.x + y1 * u2.y + y2 * u2.z + y3 * u2.w;
    cG += y0 * u3.x + y1 * u3.y + y2 * u3.z + y3 * u3.w;
  }
  red[tid] = aR;         red[512 + tid] = aZ;  red[1024 + tid] = aG;
  red[1536 + tid] = cR;  red[2048 + tid] = cZ; red[2560 + tid] = cG;
  __syncthreads();

  if (qe == 0) {
    int base = jj * 128 + b;
    float giR = red[base] + red[base + 32] + red[base + 64] + red[base + 96] + bih[j];
    float giZ = red[512 + base] + red[512 + base + 32] + red[512 + base + 64] + red[512 + base + 96] + bih[512 + j];
    float giG = red[1024 + base] + red[1024 + base + 32] + red[1024 + base + 64] + red[1024 + base + 96] + bih[1024 + j];
    float ghR = red[1536 + base] + red[1536 + base + 32] + red[1536 + base + 64] + red[1536 + base + 96] + bhh[j];
    float ghZ = red[2048 + base] + red[2048 + base + 32] + red[2048 + base + 64] + red[2048 + base + 96] + bhh[512 + j];
    float ghG = red[2560 + base] + red[2560 + base + 32] + red[2560 + base + 64] + red[2560 + base + 96] + bhh[1024 + j];
    float r = 1.f / (1.f + __expf(-(giR + ghR)));
    float z = 1.f / (1.f + __expf(-(giZ + ghZ)));
    float g = tanhf(giG + r * ghG);
    float hp = hb[j];
    float hn = (1.f - z) * g + z * hp;
    h_out[b * 512 + j] = hn;
    float xv = xr_in[b * 512 + j] + alphas[layer] * hn;
    xr_out[b * 512 + j] = xv;
    if (ys_t) ys_t[b * 512 + j] = f2bf(xv);
  }
}

// ---------------------------------------------------------------------------
extern "C" void kernel_launch(void* const* d_in, const int* in_sizes, int n_in,
                              void* d_out, int out_size, void* d_ws, size_t ws_size,
                              hipStream_t stream)
{
  (void)in_sizes; (void)n_in; (void)out_size; (void)ws_size;
  const int*   x     = (const int*)d_in[0];
  const float* enc   = (const float*)d_in[1];
  const float* hs    = (const float*)d_in[2];
  const int*   vlen  = (const int*)d_in[3];
  const float* emb   = (const float*)d_in[4];
  const float* Wq    = (const float*)d_in[5];
  const float* Wk    = (const float*)d_in[6];
  const float* Wv    = (const float*)d_in[7];
  const float* Wo    = (const float*)d_in[8];
  const float* Win   = (const float*)d_in[9];
  const float* lng   = (const float*)d_in[10];
  const float* lnb   = (const float*)d_in[11];
  const float* alph  = (const float*)d_in[12];
  const float* Wih   = (const float*)d_in[13];
  const float* Whh   = (const float*)d_in[14];
  const float* bih   = (const float*)d_in[15];
  const float* bhh   = (const float*)d_in[16];
  const float* Wd    = (const float*)d_in[17];
  const float* bd    = (const float*)d_in[18];
  float* out = (float*)d_out;

  char* ws = (char*)d_ws;
  size_t off = 0;
  auto alloc = [&](size_t bytes) -> void* {
    void* p = ws + off;
    off = (off + bytes + 255) & ~(size_t)255;
    return p;
  };
  short* Kbf     = (short*)alloc((size_t)32 * 8 * 256 * 64 * 2);
  short* Vbf     = (short*)alloc((size_t)32 * 8 * 256 * 64 * 2);
  short* WkT     = (short*)alloc((size_t)512 * 1024 * 2);
  short* WvT     = (short*)alloc((size_t)512 * 1024 * 2);
  short* WdT     = (short*)alloc((size_t)32000 * 512 * 2);
  short* WinTopT = (short*)alloc((size_t)512 * 512 * 2);
  short* WinBotT = (short*)alloc((size_t)512 * 512 * 2);
  float* Wcmb    = (float*)alloc((size_t)512 * 512 * 4);
  float* Eproj   = (float*)alloc((size_t)2048 * 512 * 4);
  float* xr0     = (float*)alloc((size_t)32 * 512 * 4);
  float* xr1     = (float*)alloc((size_t)32 * 512 * 4);
  float* h0a     = (float*)alloc((size_t)32 * 512 * 4);
  float* h0b     = (float*)alloc((size_t)32 * 512 * 4);
  float* h1a     = (float*)alloc((size_t)32 * 512 * 4);
  float* h1b     = (float*)alloc((size_t)32 * 512 * 4);
  short* ysbf    = (short*)alloc((size_t)2048 * 512 * 2);

  init_k<<<64, 256, 0, stream>>>(hs, h0a, h1a);

  // Transposed bf16 weight copies (GEMM B-operands are BT[N][K])
  transpose_k<short><<<dim3(16, 32), 256, 0, stream>>>(Wk, WkT, 1024, 512);
  transpose_k<short><<<dim3(16, 32), 256, 0, stream>>>(Wv, WvT, 1024, 512);
  transpose_k<short><<<dim3(1000, 16), 256, 0, stream>>>(Wd, WdT, 512, 32000);
  transpose_k<short><<<dim3(16, 16), 256, 0, stream>>>(Win, WinTopT, 512, 512);
  transpose_k<short><<<dim3(16, 16), 256, 0, stream>>>(Win + 512 * 512, WinBotT, 512, 512);

  // K/V projections: [8192,1024]@[1024,512] -> bf16 [b,h,s,d]
  gemm_k<1, 1><<<dim3(4, 64), 256, 0, stream>>>(enc, WkT, Kbf, 8192, 512, 1024, nullptr, nullptr, nullptr);
  gemm_k<1, 1><<<dim3(4, 64), 256, 0, stream>>>(enc, WvT, Vbf, 8192, 512, 1024, nullptr, nullptr, nullptr);
  // Wcmb = Wo @ Win_top  (f32 [e][j])
  gemm_k<1, 0><<<dim3(4, 4), 256, 0, stream>>>(Wo, WinTopT, Wcmb, 512, 512, 512, nullptr, nullptr, nullptr);
  // Eproj[t*32+b][j] = emb[x[b,t]] @ Win_bot
  gemm_k<2, 0><<<dim3(4, 16), 256, 0, stream>>>(nullptr, WinBotT, Eproj, 2048, 512, 512, x, emb, nullptr);

  for (int t = 0; t < 64; ++t) {
    const float* h0i = (t & 1) ? h0b : h0a;  float* h0o = (t & 1) ? h0a : h0b;
    const float* h1i = (t & 1) ? h1b : h1a;  float* h1o = (t & 1) ? h1a : h1b;
    attnxr_k<<<32, 512, 0, stream>>>(h1i, Wq, Kbf, Vbf, vlen, Wcmb,
                                     Eproj + (size_t)t * 32 * 512, xr0);
    gru_k<<<128, 512, 0, stream>>>(xr0, xr1, h0i, h0o,
                                   Wih, Whh, bih, bhh, lng, lnb,
                                   alph, 0, nullptr);
    gru_k<<<128, 512, 0, stream>>>(xr1, xr0, h1i, h1o,
                                   Wih + (size_t)1536 * 512, Whh + (size_t)1536 * 512,
                                   bih + 1536, bhh + 1536, lng + 512, lnb + 512,
                                   alph, 1, ysbf + (size_t)t * 32 * 512);
  }

  // logits: [2048,512] @ [512,32000] with (t,b)->(b,t) row permute + bias
  gemm_k<0, 2><<<dim3(250, 16), 256, 0, stream>>>(ysbf, WdT, out, 2048, 32000, 512,
                                                  nullptr, nullptr, bd);
  // hN tail (final states live in the 'a' buffers after 64 steps)
  fin_k<<<64, 256, 0, stream>>>(h0a, h1a, out + (size_t)65536000);
}